// Round 15
// baseline (769.361 us; speedup 1.0000x reference)
//
#include <hip/hip_runtime.h>
#include <hip/hip_bf16.h>

#define Hdim 256
#define Bdim 16
#define Lleaf 4096

typedef unsigned short u16;
typedef __attribute__((ext_vector_type(8))) short short8;
typedef __attribute__((ext_vector_type(4))) float f32x4;

__device__ __forceinline__ u16 f2bf(float x) {
    __hip_bfloat16 b = __float2bfloat16(x);
    return *(u16*)&b;
}
__device__ __forceinline__ float bf2f(u16 u) {
    __hip_bfloat16 b = *(__hip_bfloat16*)&u;
    return __bfloat162float(b);
}
__device__ __forceinline__ float fsig(float x) { return 1.0f / (1.0f + __expf(-x)); }
__device__ __forceinline__ float ftanh(float x) {
    float e = __expf(-2.0f * fabsf(x));
    float t = (1.0f - e) / (1.0f + e);
    return copysignf(t, x);
}

__device__ __forceinline__ void gload_lds16(const u16* gsrc, u16* ldsdst) {
    __builtin_amdgcn_global_load_lds(
        (const __attribute__((address_space(1))) unsigned int*)gsrc,
        (__attribute__((address_space(3))) unsigned int*)ldsdst, 16, 0, 0);
}

// ---------------- weight pack, fragment-major: Wpk[ng][c32][g][t][512] ----------------
__global__ void pack_weights2(const float* __restrict__ Wfl, const float* __restrict__ Wfr,
                              const float* __restrict__ Wi,  const float* __restrict__ Wo,
                              const float* __restrict__ Wc,
                              u16* __restrict__ Wpk, unsigned* barrier_cnt)
{
    if (blockIdx.x == 0 && threadIdx.x == 0) *barrier_cnt = 0u;   // init tail barrier
    int blk = blockIdx.x;            // 0..255 = ng*16 + c32
    int ng = blk >> 4, c = blk & 15;
    for (int e = threadIdx.x; e < 5120; e += 256) {
        int g = e >> 10, r = e & 1023;
        int t = r >> 9, s = r & 511;
        int lane = s >> 3, j = s & 7;
        int n = ng * 16 + (lane & 15);
        int k = c * 32 + (lane >> 4) * 8 + j;
        const float* W = (g == 0) ? Wfl : (g == 1) ? Wfr : (g == 2) ? Wi : (g == 3) ? Wo : Wc;
        float x = W[(size_t)k * Hdim + n];
        u16 hi = f2bf(x);
        u16 v = t ? f2bf(x - bf2f(hi)) : hi;
        Wpk[(size_t)blk * 5120 + e] = v;
    }
}

// ---------------- W_proj pack, fragment-major: Wppk[ng][c32][t][512], c32=0..7 ----------------
__global__ void pack_wp2(const float* __restrict__ Wp, u16* __restrict__ Wppk)
{
    int blk = blockIdx.x;            // 0..127 = ng*8 + c32
    int ng = blk >> 3, c = blk & 7;
    for (int e = threadIdx.x; e < 1024; e += 256) {
        int t = e >> 9, s = e & 511;
        int lane = s >> 3, j = s & 7;
        int n = ng * 16 + (lane & 15);
        int k = c * 32 + (lane >> 4) * 8 + j;
        float x = Wp[(size_t)k * Hdim + n];
        u16 hi = f2bf(x);
        u16 v = t ? f2bf(x - bf2f(hi)) : hi;
        Wppk[(size_t)blk * 1024 + e] = v;
    }
}

// ---------------- leaf via MFMA: 2-term (A bf16, W hi+lo), no LDS, no barriers ----------------
__global__ __launch_bounds__(256, 2) void leaf_mfma2(
    const int* __restrict__ ids, const float* __restrict__ emb,
    const u16* __restrict__ Wppk, const float* __restrict__ bp,
    u16* __restrict__ A0hi)
{
    int tid = threadIdx.x;
    int lane = tid & 63, w = tid >> 6;
    int l16 = lane & 15, quad = lane >> 4;
    int m0 = blockIdx.x * 128, ny = blockIdx.y;
    int n0 = ny * 64;

    const float* aptr[2];
#pragma unroll
    for (int mt = 0; mt < 2; mt++) {
        int m = m0 + w * 32 + mt * 16 + l16;
        aptr[mt] = emb + (size_t)ids[m] * 256 + quad * 8;
    }

    f32x4 acc[2][4];
    f32x4 zf = {0.f, 0.f, 0.f, 0.f};
#pragma unroll
    for (int i = 0; i < 2; i++)
#pragma unroll
        for (int j = 0; j < 4; j++) acc[i][j] = zf;

#pragma unroll 1
    for (int c = 0; c < 8; c++) {
        int k0 = c * 32;
        short8 bh[4], bl[4];
#pragma unroll
        for (int nt = 0; nt < 4; nt++) {
            const u16* pb = Wppk + (size_t)(((ny * 4 + nt) * 8 + c) * 2) * 512 + lane * 8;
            bh[nt] = *(const short8*)(pb);
            bl[nt] = *(const short8*)(pb + 512);
        }
        short8 ah[2];
#pragma unroll
        for (int mt = 0; mt < 2; mt++) {
            float4 a0 = *(const float4*)(aptr[mt] + k0);
            float4 a1 = *(const float4*)(aptr[mt] + k0 + 4);
            float fv[8] = {a0.x, a0.y, a0.z, a0.w, a1.x, a1.y, a1.z, a1.w};
#pragma unroll
            for (int e = 0; e < 8; e++) ah[mt][e] = (short)f2bf(fv[e]);
        }
#pragma unroll
        for (int nt = 0; nt < 4; nt++)
#pragma unroll
            for (int mt = 0; mt < 2; mt++) {
                acc[mt][nt] = __builtin_amdgcn_mfma_f32_16x16x32_bf16(ah[mt], bh[nt], acc[mt][nt], 0, 0, 0);
                acc[mt][nt] = __builtin_amdgcn_mfma_f32_16x16x32_bf16(ah[mt], bl[nt], acc[mt][nt], 0, 0, 0);
            }
    }
#pragma unroll
    for (int mt = 0; mt < 2; mt++)
#pragma unroll
        for (int nt = 0; nt < 4; nt++)
#pragma unroll
            for (int r = 0; r < 4; r++) {
                int m = m0 + w * 32 + mt * 16 + quad * 4 + r;
                int n = n0 + nt * 16 + l16;
                float h = acc[mt][nt][r] + bp[n];
                A0hi[(size_t)(m >> 1) * 512 + (m & 1) * 256 + n] = f2bf(h);
            }
}

// ---------------- big level (M >= 4096): 1-term bf16 GEMM, wave tile 64m x 16n ----------------
template <int LEAF, int WLO>
__global__ __launch_bounds__(256, 3) void level_big2(
    const u16* __restrict__ Ahi,
    const float* __restrict__ Cin,
    const u16* __restrict__ Wpk,
    const float* __restrict__ bfl, const float* __restrict__ bfr,
    const float* __restrict__ bi,  const float* __restrict__ bo,
    const float* __restrict__ bc,
    u16* __restrict__ Aohi, u16* __restrict__ Aolo, float* __restrict__ Cout,
    int M)
{
    int tid = threadIdx.x;
    int lane = tid & 63, w = tid >> 6;
    int l16 = lane & 15, quad = lane >> 4;
    int m0 = blockIdx.x * 64, n0 = blockIdx.y * 64;
    int ng = blockIdx.y * 4 + w;

    __shared__ u16 Abuf[2][8 * 512];

    const u16* asrc[2];
#pragma unroll
    for (int i = 0; i < 2; i++) {
        int fj = w * 2 + i;
        int s = fj >> 2, mf = fj & 3;
        int row = min(m0 + mf * 16 + l16, M - 1);
        asrc[i] = Ahi + (size_t)row * 512 + quad * 8 + s * 32;
    }
    const u16* pb = Wpk + (size_t)ng * 16 * 5120 + lane * 8;

    f32x4 acc[5][4];
    f32x4 zf = {0.f, 0.f, 0.f, 0.f};
#pragma unroll
    for (int g = 0; g < 5; g++)
#pragma unroll
        for (int mf = 0; mf < 4; mf++) acc[g][mf] = zf;

#pragma unroll
    for (int i = 0; i < 2; i++)
        gload_lds16(asrc[i], &Abuf[0][(w * 2 + i) * 512]);

#pragma unroll 1
    for (int c = 0; c < 8; c++) {
        __syncthreads();
        if (c < 7) {
#pragma unroll
            for (int i = 0; i < 2; i++)
                gload_lds16(asrc[i] + (c + 1) * 64, &Abuf[(c + 1) & 1][(w * 2 + i) * 512]);
        }
        const u16* ab = &Abuf[c & 1][0];
#pragma unroll
        for (int s = 0; s < 2; s++) {
            int c32 = c * 2 + s;
            short8 bh[5];
#pragma unroll
            for (int g = 0; g < 5; g++)
                bh[g] = *(const short8*)(pb + (size_t)(c32 * 10 + g * 2) * 512);
#pragma unroll
            for (int mf = 0; mf < 4; mf++) {
                short8 ah = *(const short8*)&ab[(s * 4 + mf) * 512 + lane * 8];
#pragma unroll
                for (int g = 0; g < 5; g++)
                    acc[g][mf] = __builtin_amdgcn_mfma_f32_16x16x32_bf16(ah, bh[g], acc[g][mf], 0, 0, 0);
            }
        }
    }

    int n = n0 + w * 16 + l16;
#pragma unroll
    for (int mf = 0; mf < 4; mf++)
#pragma unroll
        for (int r = 0; r < 4; r++) {
            int m = m0 + mf * 16 + quad * 4 + r;
            if (m >= M) continue;
            float fl = fsig(acc[0][mf][r] + bfl[n]);
            float fr = fsig(acc[1][mf][r] + bfr[n]);
            float ig = fsig(acc[2][mf][r] + bi[n]);
            float og = fsig(acc[3][mf][r] + bo[n]);
            float cc = ftanh(acc[4][mf][r] + bc[n]);
            float cl, cr;
            if (LEAF) {
                cl = ftanh(bf2f(Ahi[(size_t)m * 512 + n]));
                cr = ftanh(bf2f(Ahi[(size_t)m * 512 + 256 + n]));
            } else {
                cl = Cin[(size_t)(2 * m) * 256 + n];
                cr = Cin[(size_t)(2 * m + 1) * 256 + n];
            }
            float cn = fl * cl + fr * cr + ig * cc;
            Cout[(size_t)m * 256 + n] = cn;
            float h = og * ftanh(cn);
            u16 hh = f2bf(h);
            size_t ai = (size_t)(m >> 1) * 512 + (m & 1) * 256 + n;
            Aohi[ai] = hh;
            if (WLO) Aolo[ai] = f2bf(h - bf2f(hh));
        }
}

// ---------------- fused tail: levels M=2048..16 + classifier, ONE normal launch ----------------
// Grid (32,16) = 512 blocks; __launch_bounds__(256,2) + 20 KB LDS guarantees 2 blocks/CU
// co-residency (512 slots on 256 CUs) so a software generation barrier cannot deadlock.
// Generation barrier: monotone atomic counter; level L waits for count >= 512*(L+1).
__global__ __launch_bounds__(256, 2) void tree_tail2(
    const u16* Ahi0, const u16* Alo0, const float* Cin0,
    const u16* __restrict__ Wpk,
    const float* __restrict__ bfl, const float* __restrict__ bfr,
    const float* __restrict__ bi,  const float* __restrict__ bo,
    const float* __restrict__ bc,
    u16* T1, u16* T2, unsigned* bar,
    const float* __restrict__ Wcls, const float* __restrict__ bcls, float* out)
{
    int tid = threadIdx.x;
    int lane = tid & 63, w = tid >> 6;
    int l16 = lane & 15, quad = lane >> 4;
    int bx = blockIdx.x;        // 0..31
    int ng = blockIdx.y;        // 0..15

    __shared__ float red[4][5][256];   // 20 KB

    const u16* ahi = Ahi0;
    const u16* alo = Alo0;
    const float* cin = Cin0;
    int parity = 0;
    unsigned gen = 0;

    const u16* pbw = Wpk + (size_t)ng * 16 * 5120 + lane * 8;

#pragma unroll 1
    for (int M = 2048; M >= 16; M >>= 1) {
        u16* ohi = parity ? T2 : T1;
        u16* olo = ohi + (size_t)M * 256;
        float* oc = (float*)(ohi + (size_t)M * 512);

#pragma unroll 1
        for (int mb = bx * 16; mb < M; mb += 512) {
            const u16* pah = ahi + (size_t)(mb + l16) * 512 + quad * 8;
            const u16* pal = alo + (size_t)(mb + l16) * 512 + quad * 8;

            f32x4 acc[5];
            f32x4 zf = {0.f, 0.f, 0.f, 0.f};
#pragma unroll
            for (int g = 0; g < 5; g++) acc[g] = zf;

#pragma unroll
            for (int i = 0; i < 4; i++) {
                int c = w * 4 + i;
                short8 ah = *(const short8*)(pah + c * 32);
                short8 al = *(const short8*)(pal + c * 32);
#pragma unroll
                for (int g = 0; g < 5; g++) {
                    short8 bh = *(const short8*)(pbw + (size_t)(c * 10 + g * 2) * 512);
                    short8 bl = *(const short8*)(pbw + (size_t)(c * 10 + g * 2 + 1) * 512);
                    acc[g] = __builtin_amdgcn_mfma_f32_16x16x32_bf16(ah, bh, acc[g], 0, 0, 0);
                    acc[g] = __builtin_amdgcn_mfma_f32_16x16x32_bf16(al, bh, acc[g], 0, 0, 0);
                    acc[g] = __builtin_amdgcn_mfma_f32_16x16x32_bf16(ah, bl, acc[g], 0, 0, 0);
                }
            }

            __syncthreads();   // red[] reuse safety across mb iterations
#pragma unroll
            for (int g = 0; g < 5; g++)
#pragma unroll
                for (int r = 0; r < 4; r++)
                    red[w][g][(quad * 4 + r) * 16 + l16] = acc[g][r];
            __syncthreads();

            int m = mb + (tid >> 4);
            int n = ng * 16 + (tid & 15);
            {
                float z[5];
#pragma unroll
                for (int g = 0; g < 5; g++)
                    z[g] = red[0][g][tid] + red[1][g][tid] + red[2][g][tid] + red[3][g][tid];
                float fl = fsig(z[0] + bfl[n]);
                float fr = fsig(z[1] + bfr[n]);
                float ig = fsig(z[2] + bi[n]);
                float og = fsig(z[3] + bo[n]);
                float cc = ftanh(z[4] + bc[n]);
                float cl = cin[(size_t)(2 * m) * 256 + n];
                float cr = cin[(size_t)(2 * m + 1) * 256 + n];
                float cn = fl * cl + fr * cr + ig * cc;
                oc[(size_t)m * 256 + n] = cn;
                float h = og * ftanh(cn);
                u16 hh = f2bf(h);
                u16 hl = f2bf(h - bf2f(hh));
                size_t ai = (size_t)(m >> 1) * 512 + (m & 1) * 256 + n;
                ohi[ai] = hh;
                olo[ai] = hl;
            }
        }

        // ---- grid barrier (generation) ----
        gen++;
        __syncthreads();
        if (tid == 0) {
            __threadfence();                       // release: flush this block's writes
            atomicAdd(bar, 1u);
            unsigned target = 512u * gen;
            int guard = 0;
            while (atomicAdd(bar, 0u) < target && guard < (1 << 30)) {
                __builtin_amdgcn_s_sleep(8);
                guard++;
            }
            __threadfence();                       // acquire: invalidate stale lines
        }
        __syncthreads();

        ahi = ohi; alo = olo; cin = oc; parity ^= 1;
    }

    // classifier: root h (16 rows) in ahi/alo pair-layout
    if (bx == 0 && ng == 0 && tid < Bdim * 2) {
        int b = tid >> 1, cls = tid & 1;
        float s = bcls[cls];
        for (int n = 0; n < Hdim; n++) {
            size_t ai = (size_t)(b >> 1) * 512 + (b & 1) * 256 + n;
            float h = bf2f(ahi[ai]) + bf2f(alo[ai]);
            s += h * Wcls[(size_t)n * 2 + cls];
        }
        out[tid] = s;
    }
}

extern "C" void kernel_launch(void* const* d_in, const int* in_sizes, int n_in,
                              void* d_out, int out_size, void* d_ws, size_t ws_size,
                              hipStream_t stream) {
    const int*   ids  = (const int*)d_in[0];
    const float* emb  = (const float*)d_in[1];
    const float* Wp   = (const float*)d_in[2];
    const float* bp   = (const float*)d_in[3];
    const float* Wfl  = (const float*)d_in[4];
    const float* bfl  = (const float*)d_in[5];
    const float* Wfr  = (const float*)d_in[6];
    const float* bfr  = (const float*)d_in[7];
    const float* Wi   = (const float*)d_in[8];
    const float* bi   = (const float*)d_in[9];
    const float* Wo   = (const float*)d_in[10];
    const float* bo   = (const float*)d_in[11];
    const float* Wc   = (const float*)d_in[12];
    const float* bc   = (const float*)d_in[13];
    const float* Wcls = (const float*)d_in[14];
    const float* bcls = (const float*)d_in[15];

    u16* Wpk  = (u16*)d_ws;                                      // 2.62 MB
    u16* Wppk = Wpk + (size_t)256 * 5120;                        // 0.26 MB
    unsigned* bar = (unsigned*)((unsigned char*)d_ws + (3u << 20));  // barrier counter @ 3 MiB
    unsigned char* base = (unsigned char*)d_ws + (4u << 20);
    unsigned char* R1 = base;                                    // 32 MiB
    unsigned char* R2 = base + 33554432;                         // 64 MiB
    u16* T1 = (u16*)((unsigned char*)d_ws + (100u << 20));       // 4 MiB
    u16* T2 = (u16*)((unsigned char*)d_ws + (104u << 20));       // 4 MiB

    pack_weights2<<<256, 256, 0, stream>>>(Wfl, Wfr, Wi, Wo, Wc, Wpk, bar);
    pack_wp2<<<128, 256, 0, stream>>>(Wp, Wppk);

    int M0 = Bdim * Lleaf;
    leaf_mfma2<<<dim3(M0 / 128, 4), 256, 0, stream>>>(ids, emb, Wppk, bp, (u16*)R1);

    const u16* Ain_hi = (const u16*)R1;
    const u16* Ain_lo = nullptr;
    const float* Cin = nullptr;

    int lev = 1;
    for (int M = 32768; M >= 4096; M >>= 1, lev++) {
        unsigned char* ob = (lev & 1) ? R2 : R1;
        u16* Aohi = (u16*)ob;
        u16* Aolo = Aohi + (size_t)M * 256;
        float* Cout = (float*)(Aohi + (size_t)M * 512);
        if (lev == 1) {
            level_big2<1, 0><<<dim3(M / 64, 4), 256, 0, stream>>>(Ain_hi, nullptr, Wpk,
                                                                  bfl, bfr, bi, bo, bc, Aohi, Aolo, Cout, M);
        } else if (M > 4096) {
            level_big2<0, 0><<<dim3(M / 64, 4), 256, 0, stream>>>(Ain_hi, Cin, Wpk,
                                                                  bfl, bfr, bi, bo, bc, Aohi, Aolo, Cout, M);
        } else {
            level_big2<0, 1><<<dim3(M / 64, 4), 256, 0, stream>>>(Ain_hi, Cin, Wpk,
                                                                  bfl, bfr, bi, bo, bc, Aohi, Aolo, Cout, M);
        }
        Ain_hi = Aohi; Ain_lo = Aolo; Cin = Cout;
    }

    // fused tail: M=2048..16 + classifier, one normal launch with software grid barrier
    tree_tail2<<<dim3(32, 16), 256, 0, stream>>>(Ain_hi, Ain_lo, Cin, Wpk,
                                                 bfl, bfr, bi, bo, bc,
                                                 T1, T2, bar, Wcls, bcls, (float*)d_out);
}

// Round 16
// 395.853 us; speedup vs baseline: 1.9436x; 1.9436x over previous
//
#include <hip/hip_runtime.h>
#include <hip/hip_bf16.h>

#define Hdim 256
#define Bdim 16
#define Lleaf 4096

typedef unsigned short u16;
typedef __attribute__((ext_vector_type(8))) short short8;
typedef __attribute__((ext_vector_type(4))) float f32x4;

__device__ __forceinline__ u16 f2bf(float x) {
    __hip_bfloat16 b = __float2bfloat16(x);
    return *(u16*)&b;
}
__device__ __forceinline__ float bf2f(u16 u) {
    __hip_bfloat16 b = *(__hip_bfloat16*)&u;
    return __bfloat162float(b);
}
__device__ __forceinline__ float fsig(float x) { return 1.0f / (1.0f + __expf(-x)); }
__device__ __forceinline__ float ftanh(float x) {
    float e = __expf(-2.0f * fabsf(x));
    float t = (1.0f - e) / (1.0f + e);
    return copysignf(t, x);
}

__device__ __forceinline__ void gload_lds16(const u16* gsrc, u16* ldsdst) {
    __builtin_amdgcn_global_load_lds(
        (const __attribute__((address_space(1))) unsigned int*)gsrc,
        (__attribute__((address_space(3))) unsigned int*)ldsdst, 16, 0, 0);
}

// ---------------- weight pack, fragment-major: Wpk[ng][c32][g][t][512] ----------------
__global__ void pack_weights2(const float* __restrict__ Wfl, const float* __restrict__ Wfr,
                              const float* __restrict__ Wi,  const float* __restrict__ Wo,
                              const float* __restrict__ Wc,
                              u16* __restrict__ Wpk)
{
    int blk = blockIdx.x;            // 0..255 = ng*16 + c32
    int ng = blk >> 4, c = blk & 15;
    for (int e = threadIdx.x; e < 5120; e += 256) {
        int g = e >> 10, r = e & 1023;
        int t = r >> 9, s = r & 511;
        int lane = s >> 3, j = s & 7;
        int n = ng * 16 + (lane & 15);
        int k = c * 32 + (lane >> 4) * 8 + j;
        const float* W = (g == 0) ? Wfl : (g == 1) ? Wfr : (g == 2) ? Wi : (g == 3) ? Wo : Wc;
        float x = W[(size_t)k * Hdim + n];
        u16 hi = f2bf(x);
        u16 v = t ? f2bf(x - bf2f(hi)) : hi;
        Wpk[(size_t)blk * 5120 + e] = v;
    }
}

// ---------------- W_proj pack, fragment-major: Wppk[ng][c32][t][512], c32=0..7 ----------------
__global__ void pack_wp2(const float* __restrict__ Wp, u16* __restrict__ Wppk)
{
    int blk = blockIdx.x;            // 0..127 = ng*8 + c32
    int ng = blk >> 3, c = blk & 7;
    for (int e = threadIdx.x; e < 1024; e += 256) {
        int t = e >> 9, s = e & 511;
        int lane = s >> 3, j = s & 7;
        int n = ng * 16 + (lane & 15);
        int k = c * 32 + (lane >> 4) * 8 + j;
        float x = Wp[(size_t)k * Hdim + n];
        u16 hi = f2bf(x);
        u16 v = t ? f2bf(x - bf2f(hi)) : hi;
        Wppk[(size_t)blk * 1024 + e] = v;
    }
}

// ---------------- leaf via MFMA: 2-term (A bf16, W hi+lo), no LDS, no barriers ----------------
__global__ __launch_bounds__(256, 2) void leaf_mfma2(
    const int* __restrict__ ids, const float* __restrict__ emb,
    const u16* __restrict__ Wppk, const float* __restrict__ bp,
    u16* __restrict__ A0hi)
{
    int tid = threadIdx.x;
    int lane = tid & 63, w = tid >> 6;
    int l16 = lane & 15, quad = lane >> 4;
    int m0 = blockIdx.x * 128, ny = blockIdx.y;
    int n0 = ny * 64;

    const float* aptr[2];
#pragma unroll
    for (int mt = 0; mt < 2; mt++) {
        int m = m0 + w * 32 + mt * 16 + l16;
        aptr[mt] = emb + (size_t)ids[m] * 256 + quad * 8;
    }

    f32x4 acc[2][4];
    f32x4 zf = {0.f, 0.f, 0.f, 0.f};
#pragma unroll
    for (int i = 0; i < 2; i++)
#pragma unroll
        for (int j = 0; j < 4; j++) acc[i][j] = zf;

#pragma unroll 1
    for (int c = 0; c < 8; c++) {
        int k0 = c * 32;
        short8 bh[4], bl[4];
#pragma unroll
        for (int nt = 0; nt < 4; nt++) {
            const u16* pb = Wppk + (size_t)(((ny * 4 + nt) * 8 + c) * 2) * 512 + lane * 8;
            bh[nt] = *(const short8*)(pb);
            bl[nt] = *(const short8*)(pb + 512);
        }
        short8 ah[2];
#pragma unroll
        for (int mt = 0; mt < 2; mt++) {
            float4 a0 = *(const float4*)(aptr[mt] + k0);
            float4 a1 = *(const float4*)(aptr[mt] + k0 + 4);
            float fv[8] = {a0.x, a0.y, a0.z, a0.w, a1.x, a1.y, a1.z, a1.w};
#pragma unroll
            for (int e = 0; e < 8; e++) ah[mt][e] = (short)f2bf(fv[e]);
        }
#pragma unroll
        for (int nt = 0; nt < 4; nt++)
#pragma unroll
            for (int mt = 0; mt < 2; mt++) {
                acc[mt][nt] = __builtin_amdgcn_mfma_f32_16x16x32_bf16(ah[mt], bh[nt], acc[mt][nt], 0, 0, 0);
                acc[mt][nt] = __builtin_amdgcn_mfma_f32_16x16x32_bf16(ah[mt], bl[nt], acc[mt][nt], 0, 0, 0);
            }
    }
#pragma unroll
    for (int mt = 0; mt < 2; mt++)
#pragma unroll
        for (int nt = 0; nt < 4; nt++)
#pragma unroll
            for (int r = 0; r < 4; r++) {
                int m = m0 + w * 32 + mt * 16 + quad * 4 + r;
                int n = n0 + nt * 16 + l16;
                float h = acc[mt][nt][r] + bp[n];
                A0hi[(size_t)(m >> 1) * 512 + (m & 1) * 256 + n] = f2bf(h);
            }
}

// ---------------- big level (M >= 4096): 1-term bf16 GEMM, wave tile 64m x 16n ----------------
template <int LEAF, int WLO>
__global__ __launch_bounds__(256, 3) void level_big2(
    const u16* __restrict__ Ahi,
    const float* __restrict__ Cin,
    const u16* __restrict__ Wpk,
    const float* __restrict__ bfl, const float* __restrict__ bfr,
    const float* __restrict__ bi,  const float* __restrict__ bo,
    const float* __restrict__ bc,
    u16* __restrict__ Aohi, u16* __restrict__ Aolo, float* __restrict__ Cout,
    int M)
{
    int tid = threadIdx.x;
    int lane = tid & 63, w = tid >> 6;
    int l16 = lane & 15, quad = lane >> 4;
    int m0 = blockIdx.x * 64, n0 = blockIdx.y * 64;
    int ng = blockIdx.y * 4 + w;

    __shared__ u16 Abuf[2][8 * 512];

    const u16* asrc[2];
#pragma unroll
    for (int i = 0; i < 2; i++) {
        int fj = w * 2 + i;
        int s = fj >> 2, mf = fj & 3;
        int row = min(m0 + mf * 16 + l16, M - 1);
        asrc[i] = Ahi + (size_t)row * 512 + quad * 8 + s * 32;
    }
    const u16* pb = Wpk + (size_t)ng * 16 * 5120 + lane * 8;

    f32x4 acc[5][4];
    f32x4 zf = {0.f, 0.f, 0.f, 0.f};
#pragma unroll
    for (int g = 0; g < 5; g++)
#pragma unroll
        for (int mf = 0; mf < 4; mf++) acc[g][mf] = zf;

#pragma unroll
    for (int i = 0; i < 2; i++)
        gload_lds16(asrc[i], &Abuf[0][(w * 2 + i) * 512]);

#pragma unroll 1
    for (int c = 0; c < 8; c++) {
        __syncthreads();
        if (c < 7) {
#pragma unroll
            for (int i = 0; i < 2; i++)
                gload_lds16(asrc[i] + (c + 1) * 64, &Abuf[(c + 1) & 1][(w * 2 + i) * 512]);
        }
        const u16* ab = &Abuf[c & 1][0];
#pragma unroll
        for (int s = 0; s < 2; s++) {
            int c32 = c * 2 + s;
            short8 bh[5];
#pragma unroll
            for (int g = 0; g < 5; g++)
                bh[g] = *(const short8*)(pb + (size_t)(c32 * 10 + g * 2) * 512);
#pragma unroll
            for (int mf = 0; mf < 4; mf++) {
                short8 ah = *(const short8*)&ab[(s * 4 + mf) * 512 + lane * 8];
#pragma unroll
                for (int g = 0; g < 5; g++)
                    acc[g][mf] = __builtin_amdgcn_mfma_f32_16x16x32_bf16(ah, bh[g], acc[g][mf], 0, 0, 0);
            }
        }
    }

    int n = n0 + w * 16 + l16;
#pragma unroll
    for (int mf = 0; mf < 4; mf++)
#pragma unroll
        for (int r = 0; r < 4; r++) {
            int m = m0 + mf * 16 + quad * 4 + r;
            if (m >= M) continue;
            float fl = fsig(acc[0][mf][r] + bfl[n]);
            float fr = fsig(acc[1][mf][r] + bfr[n]);
            float ig = fsig(acc[2][mf][r] + bi[n]);
            float og = fsig(acc[3][mf][r] + bo[n]);
            float cc = ftanh(acc[4][mf][r] + bc[n]);
            float cl, cr;
            if (LEAF) {
                cl = ftanh(bf2f(Ahi[(size_t)m * 512 + n]));
                cr = ftanh(bf2f(Ahi[(size_t)m * 512 + 256 + n]));
            } else {
                cl = Cin[(size_t)(2 * m) * 256 + n];
                cr = Cin[(size_t)(2 * m + 1) * 256 + n];
            }
            float cn = fl * cl + fr * cr + ig * cc;
            Cout[(size_t)m * 256 + n] = cn;
            float h = og * ftanh(cn);
            u16 hh = f2bf(h);
            size_t ai = (size_t)(m >> 1) * 512 + (m & 1) * 256 + n;
            Aohi[ai] = hh;
            if (WLO) Aolo[ai] = f2bf(h - bf2f(hh));
        }
}

// ---------------- small level (M <= 2048): 16m x 16n x 5g, waves split K, 3-term --------------
// mode 0: normal. mode 1 (M=32): additionally seed out[b,cls] = bcls[cls].
// mode 2 (M=16): fused classifier — shfl-reduce h*Wcls over the 16-lane n-slice, atomicAdd out.
__global__ __launch_bounds__(256, 4) void level_small(
    const u16* __restrict__ Ahi, const u16* __restrict__ Alo,
    const float* __restrict__ Cin,
    const u16* __restrict__ Wpk,
    const float* __restrict__ bfl, const float* __restrict__ bfr,
    const float* __restrict__ bi,  const float* __restrict__ bo,
    const float* __restrict__ bc,
    u16* __restrict__ Aohi, u16* __restrict__ Aolo, float* __restrict__ Cout,
    int M, int mode,
    const float* __restrict__ Wcls, const float* __restrict__ bcls, float* __restrict__ out)
{
    int tid = threadIdx.x;
    int lane = tid & 63, w = tid >> 6;
    int l16 = lane & 15, quad = lane >> 4;
    int mb = blockIdx.x * 16;
    int ng = blockIdx.y;

    if (mode == 1 && blockIdx.x == 0 && blockIdx.y == 0 && tid < Bdim * 2)
        out[tid] = bcls[tid & 1];

    const u16* pah = Ahi + (size_t)(mb + l16) * 512 + quad * 8;
    const u16* pal = Alo + (size_t)(mb + l16) * 512 + quad * 8;
    const u16* pb  = Wpk + (size_t)ng * 16 * 5120 + lane * 8;

    f32x4 acc[5];
    f32x4 zf = {0.f, 0.f, 0.f, 0.f};
#pragma unroll
    for (int g = 0; g < 5; g++) acc[g] = zf;

#pragma unroll
    for (int i = 0; i < 4; i++) {
        int c = w * 4 + i;
        short8 ah = *(const short8*)(pah + c * 32);
        short8 al = *(const short8*)(pal + c * 32);
#pragma unroll
        for (int g = 0; g < 5; g++) {
            short8 bh = *(const short8*)(pb + (size_t)(c * 10 + g * 2) * 512);
            short8 bl = *(const short8*)(pb + (size_t)(c * 10 + g * 2 + 1) * 512);
            acc[g] = __builtin_amdgcn_mfma_f32_16x16x32_bf16(ah, bh, acc[g], 0, 0, 0);
            acc[g] = __builtin_amdgcn_mfma_f32_16x16x32_bf16(al, bh, acc[g], 0, 0, 0);
            acc[g] = __builtin_amdgcn_mfma_f32_16x16x32_bf16(ah, bl, acc[g], 0, 0, 0);
        }
    }

    __shared__ float red[4][5][256];   // 20 KB
#pragma unroll
    for (int g = 0; g < 5; g++)
#pragma unroll
        for (int r = 0; r < 4; r++)
            red[w][g][(quad * 4 + r) * 16 + l16] = acc[g][r];
    __syncthreads();

    int m = mb + (tid >> 4);
    int n = ng * 16 + (tid & 15);
    if (m < M) {
        float z[5];
#pragma unroll
        for (int g = 0; g < 5; g++)
            z[g] = red[0][g][tid] + red[1][g][tid] + red[2][g][tid] + red[3][g][tid];
        float fl = fsig(z[0] + bfl[n]);
        float fr = fsig(z[1] + bfr[n]);
        float ig = fsig(z[2] + bi[n]);
        float og = fsig(z[3] + bo[n]);
        float cc = ftanh(z[4] + bc[n]);
        float cl = Cin[(size_t)(2 * m) * 256 + n];
        float cr = Cin[(size_t)(2 * m + 1) * 256 + n];
        float cn = fl * cl + fr * cr + ig * cc;
        Cout[(size_t)m * 256 + n] = cn;
        float h = og * ftanh(cn);
        u16 hh = f2bf(h);
        u16 hl = f2bf(h - bf2f(hh));
        size_t ai = (size_t)(m >> 1) * 512 + (m & 1) * 256 + n;
        Aohi[ai] = hh;
        Aolo[ai] = hl;
        if (mode == 2) {
            // fused classifier: reduce h*Wcls over this 16-lane n-slice
            float p0 = h * Wcls[(size_t)n * 2 + 0];
            float p1 = h * Wcls[(size_t)n * 2 + 1];
#pragma unroll
            for (int off = 8; off >= 1; off >>= 1) {
                p0 += __shfl_xor(p0, off);
                p1 += __shfl_xor(p1, off);
            }
            if ((tid & 15) == 0) {
                atomicAdd(&out[m * 2 + 0], p0);
                atomicAdd(&out[m * 2 + 1], p1);
            }
        }
    }
}

extern "C" void kernel_launch(void* const* d_in, const int* in_sizes, int n_in,
                              void* d_out, int out_size, void* d_ws, size_t ws_size,
                              hipStream_t stream) {
    const int*   ids  = (const int*)d_in[0];
    const float* emb  = (const float*)d_in[1];
    const float* Wp   = (const float*)d_in[2];
    const float* bp   = (const float*)d_in[3];
    const float* Wfl  = (const float*)d_in[4];
    const float* bfl  = (const float*)d_in[5];
    const float* Wfr  = (const float*)d_in[6];
    const float* bfr  = (const float*)d_in[7];
    const float* Wi   = (const float*)d_in[8];
    const float* bi   = (const float*)d_in[9];
    const float* Wo   = (const float*)d_in[10];
    const float* bo   = (const float*)d_in[11];
    const float* Wc   = (const float*)d_in[12];
    const float* bc   = (const float*)d_in[13];
    const float* Wcls = (const float*)d_in[14];
    const float* bcls = (const float*)d_in[15];

    u16* Wpk  = (u16*)d_ws;                                      // 2.62 MB
    u16* Wppk = Wpk + (size_t)256 * 5120;                        // 0.26 MB
    unsigned char* base = (unsigned char*)d_ws + (4u << 20);
    unsigned char* R1 = base;                                    // 32 MiB
    unsigned char* R2 = base + 33554432;                         // 64 MiB

    pack_weights2<<<256, 256, 0, stream>>>(Wfl, Wfr, Wi, Wo, Wc, Wpk);
    pack_wp2<<<128, 256, 0, stream>>>(Wp, Wppk);

    int M0 = Bdim * Lleaf;
    leaf_mfma2<<<dim3(M0 / 128, 4), 256, 0, stream>>>(ids, emb, Wppk, bp, (u16*)R1);

    const u16* Ain_hi = (const u16*)R1;
    const u16* Ain_lo = nullptr;
    const float* Cin = nullptr;

    int lev = 1;
    for (int M = 32768; M >= 16; M >>= 1, lev++) {
        unsigned char* ob = (lev & 1) ? R2 : R1;
        u16* Aohi = (u16*)ob;
        u16* Aolo = Aohi + (size_t)M * 256;
        float* Cout = (float*)(Aohi + (size_t)M * 512);
        if (lev == 1) {
            level_big2<1, 0><<<dim3(M / 64, 4), 256, 0, stream>>>(Ain_hi, nullptr, Wpk,
                                                                  bfl, bfr, bi, bo, bc, Aohi, Aolo, Cout, M);
        } else if (M > 4096) {
            level_big2<0, 0><<<dim3(M / 64, 4), 256, 0, stream>>>(Ain_hi, Cin, Wpk,
                                                                  bfl, bfr, bi, bo, bc, Aohi, Aolo, Cout, M);
        } else if (M == 4096) {
            level_big2<0, 1><<<dim3(M / 64, 4), 256, 0, stream>>>(Ain_hi, Cin, Wpk,
                                                                  bfl, bfr, bi, bo, bc, Aohi, Aolo, Cout, M);
        } else {
            int mode = (M == 32) ? 1 : (M == 16) ? 2 : 0;
            level_small<<<dim3(M / 16, 16), 256, 0, stream>>>(Ain_hi, Ain_lo, Cin, Wpk,
                                                              bfl, bfr, bi, bo, bc, Aohi, Aolo, Cout,
                                                              M, mode, Wcls, bcls, (float*)d_out);
        }
        Ain_hi = Aohi; Ain_lo = Aolo; Cin = Cout;
    }
}